// Round 9
// baseline (463.715 us; speedup 1.0000x reference)
//
#include <hip/hip_runtime.h>
#include <hip/hip_bf16.h>

#define ALPHA 0.2f

typedef __attribute__((ext_vector_type(8)))  __bf16 bf16x8;
typedef int          i32x4 __attribute__((ext_vector_type(4)));
typedef float        f32x4 __attribute__((ext_vector_type(4)));
typedef unsigned int u32x4 __attribute__((ext_vector_type(4)));

static __device__ __forceinline__ unsigned short bf16bits(float v) {
    __bf16 b = (__bf16)v;
    unsigned short u;
    __builtin_memcpy(&u, &b, 2);
    return u;
}

// ---------- Kernel 1: h = x*W ; f1 = h@a1 ; f2 = h@a2 ; hB = 16x16x32 B-fragment-packed h ----------
// hB layout: frag id = ks32*8 + ft16  (ks32 = j/32, ft16 = f/16), 512 bf16 per frag:
//   element(lane s, e) = h[j = ks32*32 + (s>>4)*8 + e][f = ft16*16 + (s&15)] at frag*512 + s*8 + e
__global__ __launch_bounds__(256) void gat_prep(
    const float* __restrict__ x, const float* __restrict__ W, const float* __restrict__ a,
    float* __restrict__ f1, float* __restrict__ f2, unsigned short* __restrict__ hB,
    float* __restrict__ ws_acc)
{
    __shared__ unsigned short lh[32][136];   // [j-local][f]
    int t = threadIdx.x;
    int i0 = blockIdx.x * 32;
    if (blockIdx.x == 0 && t < 128) ws_acc[t] = 0.0f;

    int row = t >> 3, q = t & 7;             // 8 threads per row, 16 f each
    int i = i0 + row;
    const float4* xp  = (const float4*)(x + (size_t)i * 128 + q * 16);
    const float4* wp  = (const float4*)(W + (size_t)i * 128 + q * 16);
    const float4* a1p = (const float4*)(a + q * 16);
    const float4* a2p = (const float4*)(a + 128 + q * 16);
    float p1 = 0.f, p2 = 0.f;
    #pragma unroll
    for (int jj = 0; jj < 4; ++jj) {
        float4 xv = xp[jj], wv = wp[jj], a1v = a1p[jj], a2v = a2p[jj];
        float h0 = xv.x * wv.x, h1 = xv.y * wv.y, h2 = xv.z * wv.z, h3 = xv.w * wv.w;
        p1 += h0 * a1v.x + h1 * a1v.y + h2 * a1v.z + h3 * a1v.w;
        p2 += h0 * a2v.x + h1 * a2v.y + h2 * a2v.z + h3 * a2v.w;
        int fb = q * 16 + jj * 4;
        lh[row][fb + 0] = bf16bits(h0);
        lh[row][fb + 1] = bf16bits(h1);
        lh[row][fb + 2] = bf16bits(h2);
        lh[row][fb + 3] = bf16bits(h3);
    }
    p1 += __shfl_xor(p1, 1); p1 += __shfl_xor(p1, 2); p1 += __shfl_xor(p1, 4);
    p2 += __shfl_xor(p2, 1); p2 += __shfl_xor(p2, 2); p2 += __shfl_xor(p2, 4);
    if (q == 0) { f1[i] = p1; f2[i] = p2; }
    __syncthreads();

    // fragment-pack: this block is exactly ks32 = blockIdx.x (32 j rows)
    int ftl = t >> 5, s0 = t & 31;
    size_t fragbase = ((size_t)blockIdx.x * 8 + ftl) * 512;
    #pragma unroll
    for (int hw = 0; hw < 2; ++hw) {
        int s = s0 + hw * 32;
        int jl = (s >> 4) * 8;
        int f = ftl * 16 + (s & 15);
        unsigned int p[4];
        #pragma unroll
        for (int k = 0; k < 4; ++k) {
            unsigned int lo = lh[jl + 2 * k][f];
            unsigned int hi = lh[jl + 2 * k + 1][f];
            p[k] = lo | (hi << 16);
        }
        u32x4 v = {p[0], p[1], p[2], p[3]};
        *(u32x4*)(hB + fragbase + s * 8) = v;
    }
}

// ---------- Kernel 2: wave-autonomous fused attention + adj@W2 row sums ----------
// 512 blocks x 256 threads (4 waves). Block owns 16 rows; wave w owns j in [w*2048,(w+1)*2048),
// processed as 32 chunks of 64 j. R9 delta vs R8: monotone-FIFO schedule. Per chunk the
// VMEM issue order is [16 B-frags (chunk c)] [adj (chunk c+1)]; consume waits only the OLD
// adj (high vmcnt, leaves B+new adj in flight); MFMA waits B which is OLDER than the new
// adj, so the adj stream stays in flight across the whole period. (R8's order made every
// B-wait drain the just-issued adj chunk — vmcnt bounds TOTAL outstanding, in issue order —
// serializing HBM and L2 streams; measured 27k cyc/chunk matched that model.)
// Epilogue reduction now uses a DEDICATED LDS buffer (no tile reuse, no race class).
__global__ __launch_bounds__(256, 2) void gat_main(
    const int* __restrict__ adj, const float* __restrict__ x,
    const float* __restrict__ W2, const float* __restrict__ f1g,
    const float* __restrict__ f2g, const unsigned short* __restrict__ hB,
    float* __restrict__ hp, float* __restrict__ ws_acc)
{
    __shared__ unsigned short tile[4][16][72];   // per-wave private A-tiles (16x64 wg, pad->bank-spread)
    __shared__ float redbuf[3][2048];            // dedicated epilogue acc-reduction buffer
    __shared__ float den_s[4][16], rs_s[4][16];

    int tid = threadIdx.x;
    int w = tid >> 6, l = tid & 63;
    int i0 = blockIdx.x * 16;

    float f1r[16];
    #pragma unroll
    for (int r = 0; r < 16; ++r) f1r[r] = f1g[i0 + r];

    float den[16], rs[16];
    #pragma unroll
    for (int r = 0; r < 16; ++r) { den[r] = 0.f; rs[r] = 0.f; }
    f32x4 acc[8] = {};

    const int jb = w * 2048;
    const int* arow = adj + (size_t)i0 * 8192 + jb + l;
    const float* f2p = f2g + jb + l;
    const float* w2p = W2 + jb + l;

    int adjreg[2][16];
    float f2v[2], w2v[2];
    auto issueAdj = [&](int c, int buf) {
        int jo = c * 64;
        f2v[buf] = f2p[jo];
        w2v[buf] = w2p[jo];
        #pragma unroll
        for (int r = 0; r < 16; ++r)
            adjreg[buf][r] = __builtin_nontemporal_load(arow + (size_t)r * 8192 + jo);
    };
    issueAdj(0, 0);

    // wave's ks-quarter of hB: ks32 base = w*64; chunk c covers ks32 = w*64 + 2c (+0,1)
    const unsigned short* hBw = hB + (size_t)w * 262144 + l * 8;
    const unsigned short* ap  = &tile[w][l & 15][(l >> 4) * 8];   // A-frag base

    for (int c = 0; c < 32; ++c) {
        int cur = c & 1;
        // ---- 1. issue ALL B-frags for chunk c (oldest in this period's FIFO) ----
        const unsigned short* bp = hBw + (size_t)c * 8192;
        bf16x8 bbuf[16];
        #pragma unroll
        for (int t2 = 0; t2 < 16; ++t2)
            bbuf[t2] = *(const bf16x8*)(bp + t2 * 512);
        // ---- 2. issue adj(c+1) (newest; stays in flight through consume+MFMA) ----
        if (c < 31) issueAdj(c + 1, cur ^ 1);
        // ---- 3. consume chunk c (adj(c) issued a full period ago -> landed) ----
        float cf2 = f2v[cur], cw2 = w2v[cur];
        #pragma unroll
        for (int r = 0; r < 16; ++r) {
            int ad = adjreg[cur][r];
            float tt = f1r[r] + cf2;
            float lr = fmaxf(tt, ALPHA * tt);     // leakyrelu
            float ex = __expf(lr);
            float gg = (ad != 0) ? ex : 0.0f;
            den[r] += gg;
            rs[r] += (ad != 0) ? cw2 : 0.0f;
            tile[w][r][l] = bf16bits(gg);
        }
        // ---- 4. MFMA chunk c (B waits leave the newer adj stream in flight) ----
        #pragma unroll
        for (int ksl = 0; ksl < 2; ++ksl) {
            bf16x8 af = *(const bf16x8*)(ap + ksl * 32);
            #pragma unroll
            for (int ft = 0; ft < 8; ++ft)
                acc[ft] = __builtin_amdgcn_mfma_f32_16x16x32_bf16(af, bbuf[ksl * 8 + ft], acc[ft], 0, 0, 0);
        }
    }

    // ---- lane reduction of den/rs, stash per-wave sums ----
    #pragma unroll
    for (int r = 0; r < 16; ++r) {
        float d = den[r], rr = rs[r];
        #pragma unroll
        for (int off = 1; off < 64; off <<= 1) {
            d += __shfl_xor(d, off);
            rr += __shfl_xor(rr, off);
        }
        if (l == 0) { den_s[w][r] = d; rs_s[w][r] = rr; }
    }

    // ---- 4-way j-split acc reduction via dedicated buffer (single barrier) ----
    float* av = (float*)acc;
    if (w != 0) {
        float* dst = &redbuf[w - 1][0];
        #pragma unroll
        for (int j = 0; j < 32; ++j) dst[j * 64 + l] = av[j];
    }
    __syncthreads();

    if (w == 0) {
        #pragma unroll
        for (int ww = 0; ww < 3; ++ww) {
            const float* srcp = &redbuf[ww][0];
            #pragma unroll
            for (int j = 0; j < 32; ++j) av[j] += srcp[j * 64 + l];
        }
        int q = l >> 4, col = l & 15;
        float inv[4];
        #pragma unroll
        for (int reg = 0; reg < 4; ++reg) {
            int row = q * 4 + reg;
            float dsum = den_s[0][row] + den_s[1][row] + den_s[2][row] + den_s[3][row];
            inv[reg] = (dsum != 0.f) ? 1.0f / dsum : 0.f;
        }
        #pragma unroll
        for (int ft = 0; ft < 8; ++ft) {
            #pragma unroll
            for (int reg = 0; reg < 4; ++reg) {
                int row = q * 4 + reg;
                __builtin_nontemporal_store(acc[ft][reg] * inv[reg],
                    hp + (size_t)(i0 + row) * 128 + ft * 16 + col);
            }
        }
    } else if (w == 1) {
        // out-path partial: sum_i rs[i] * x[i][:] over this block's 16 rows
        float px = 0.f, py = 0.f;
        #pragma unroll
        for (int r = 0; r < 16; ++r) {
            float rm = rs_s[0][r] + rs_s[1][r] + rs_s[2][r] + rs_s[3][r];
            const float* xr = x + (size_t)(i0 + r) * 128;
            px += rm * xr[l];
            py += rm * xr[l + 64];
        }
        atomicAdd(ws_acc + l, px);
        atomicAdd(ws_acc + l + 64, py);
    }
}

// ---------- Kernel 3: elu epilogue ----------
__global__ __launch_bounds__(128) void gat_finish(const float* __restrict__ ws_acc,
                                                  float* __restrict__ out)
{
    int t = threadIdx.x;
    float v = ws_acc[t];
    out[t] = (v > 0.f) ? v : (__expf(v) - 1.0f);
}

extern "C" void kernel_launch(void* const* d_in, const int* in_sizes, int n_in,
                              void* d_out, int out_size, void* d_ws, size_t ws_size,
                              hipStream_t stream) {
    const float* x   = (const float*)d_in[0];
    const int*   adj = (const int*)d_in[1];
    const float* W   = (const float*)d_in[2];
    const float* a   = (const float*)d_in[3];
    const float* W2  = (const float*)d_in[4];
    float* out = (float*)d_out;              // [0:128] elu out, [128:] h_prime [8192][128]

    float* wsf    = (float*)d_ws;
    float* ws_acc = wsf;                     // 128 floats
    float* f1     = wsf + 128;               // 8192 floats
    float* f2     = wsf + 128 + 8192;        // 8192 floats
    unsigned short* hB = (unsigned short*)(wsf + 128 + 2 * 8192);  // bf16, 2 MB fragment-packed

    gat_prep<<<256, 256, 0, stream>>>(x, W, a, f1, f2, hB, ws_acc);
    gat_main<<<512, 256, 0, stream>>>(adj, x, W2, f1, f2, hB, out + 128, ws_acc);
    gat_finish<<<1, 128, 0, stream>>>(ws_acc, out);
}